// Round 3
// baseline (141.369 us; speedup 1.0000x reference)
//
#include <hip/hip_runtime.h>

#define N_HEAD 16
#define DHEAD 64
#define TSEQ 2048
#define DMODEL 1024
#define BATCH 2

typedef _Float16 f16x8 __attribute__((ext_vector_type(8)));
typedef _Float16 f16x4 __attribute__((ext_vector_type(4)));
typedef _Float16 f16x2 __attribute__((ext_vector_type(2)));
typedef __fp16 fp16x2 __attribute__((ext_vector_type(2)));
typedef float f32x4 __attribute__((ext_vector_type(4)));

union F8 { f16x8 v; uint4 u; f16x2 h[4]; };
union F4 { f16x4 v; uint2 u; f16x2 h[2]; };

#if __has_builtin(__builtin_amdgcn_exp2f)
#define EXP2F(x) __builtin_amdgcn_exp2f(x)
#else
#define EXP2F(x) exp2f(x)
#endif

// async global->LDS: HW writes lane i's 16B at (wave-uniform lds base) + i*16
__device__ __forceinline__ void gload_lds16(const void* g, void* l) {
    __builtin_amdgcn_global_load_lds(
        (const __attribute__((address_space(1))) void*)g,
        (__attribute__((address_space(3))) void*)l, 16, 0, 0);
}

// v_cvt_pkrtz_f16_f32: pack two fp32 -> two f16 (RTZ)
__device__ __forceinline__ f16x2 pk(float a, float b) {
    union { fp16x2 i; f16x2 o; } c;
    c.i = __builtin_amdgcn_cvt_pkrtz(a, b);
    return c.o;
}

__device__ __forceinline__ F8 pack8_f32(const float* p) {
    const float4 a = *(const float4*)p;
    const float4 b = *(const float4*)(p + 4);
    F8 r;
    r.h[0] = pk(a.x, a.y); r.h[1] = pk(a.z, a.w);
    r.h[2] = pk(b.x, b.y); r.h[3] = pk(b.z, b.w);
    return r;
}

// Prepass: K [B,S,DMODEL] f32 -> Kh [BH,S,64] f16 (head-major)
//          V [B,S,DMODEL] f32 -> Vh [BH,64,S] f16 (transposed)
__global__ __launch_bounds__(256) void prep(const float* __restrict__ K,
                                            const float* __restrict__ V,
                                            _Float16* __restrict__ Kh,
                                            _Float16* __restrict__ Vh)
{
    __shared__ float tl[64][67];
    const int bh = blockIdx.y, b = bh >> 4, h = bh & 15;
    const int s0 = blockIdx.x * 64;
    const int t = threadIdx.x;
    const int r16 = t >> 4, c4 = (t & 15) * 4;
    #pragma unroll
    for (int pass = 0; pass < 4; ++pass) {
        const int row = pass * 16 + r16;
        const size_t goff = ((size_t)(b * TSEQ + s0 + row)) * DMODEL + h * DHEAD + c4;
        const float4 fk = *(const float4*)(K + goff);
        F4 ok;
        ok.h[0] = pk(fk.x, fk.y);
        ok.h[1] = pk(fk.z, fk.w);
        *(uint2*)(Kh + (((size_t)bh * TSEQ + s0 + row) << 6) + c4) = ok.u;
        const float4 fv = *(const float4*)(V + goff);
        tl[row][c4 + 0] = fv.x; tl[row][c4 + 1] = fv.y;
        tl[row][c4 + 2] = fv.z; tl[row][c4 + 3] = fv.w;
    }
    __syncthreads();
    const int d = t >> 2, sc = (t & 3) * 16;
    F8 p0, p1;
    #pragma unroll
    for (int j = 0; j < 4; ++j) p0.h[j] = pk(tl[sc + 2 * j][d], tl[sc + 2 * j + 1][d]);
    #pragma unroll
    for (int j = 0; j < 4; ++j) p1.h[j] = pk(tl[sc + 8 + 2 * j][d], tl[sc + 9 + 2 * j][d]);
    _Float16* vo = Vh + ((size_t)bh * DHEAD + d) * TSEQ + s0 + sc;
    *(uint4*)vo = p0.u;
    *(uint4*)(vo + 8) = p1.u;
}

// 128 q-rows per block (two 16-row strips per wave): each wave's full-tile
// K/V LDS read now feeds 2x the output -> LDS bytes/FLOP halved (LDS BW is
// the measured bottleneck: ~1700 CU-cycles per 64-q block-iter, residency-
// independent). Grid 32x16 = 512 blocks = 2/CU.
__global__ __launch_bounds__(256, 2) void alibi_attn(
    const float* __restrict__ Q, const _Float16* __restrict__ Kh,
    const _Float16* __restrict__ Vh, float* __restrict__ O)
{
    // double-buffered 64x64 f16 KV tiles, XOR-swizzled 16B chunks:
    // data chunk (row, c) lives at LDS slot (row, c ^ (row&7))
    __shared__ __align__(16) char kbuf[2][8192];
    __shared__ __align__(16) char vbuf[2][8192];

    const int wv   = threadIdx.x >> 6;
    const int lane = threadIdx.x & 63;
    const int quad = lane >> 4;
    const int l16  = lane & 15;

    const int bh = blockIdx.x;
    const int b  = bh >> 4, h = bh & 15;
    // q-tile pairing: linear dispatch puts py=p and py=p+8 on the same CU;
    // qt = {15-p, p} -> per-CU iteration total (32-2p)+(2p+2) = 34, constant.
    const int py = blockIdx.y;
    const int qt = (py < 8) ? (15 - py) : (py - 8);
    const int sx2 = 2 * qt + 1;            // last s-tile index (diag of strip 1)

    const float LOG2E   = 1.44269504088896f;
    const float slope   = exp2f(-0.5f * (float)(h + 1));
    const float bslope2 = slope * LOG2E;
    const float sscale2 = 0.125f * LOG2E;
    const float step64  = 64.0f * bslope2;
    const float rb1 = bslope2, rb2 = 2.f * bslope2, rb3 = 3.f * bslope2;

    const float* qp  = Q + (size_t)b * TSEQ * DMODEL + (size_t)h * DHEAD;
    const char*  kpb = (const char*)(Kh + (size_t)bh * TSEQ * DHEAD);
    const char*  vpb = (const char*)(Vh + (size_t)bh * DHEAD * TSEQ);

    // staging constants: lane i -> LDS slot (row gr + i/8, chunk i&7);
    // source chunk = (i&7) ^ (i/8) so slot sc holds data chunk sc^(row&7)
    const int st_r  = lane >> 3;
    const int k_src = st_r * 128  + (((lane & 7) ^ st_r) * 16);
    const int v_src = st_r * 4096 + (((lane & 7) ^ st_r) * 16);

    // fragment LDS offsets (loop-invariant)
    const int koff0 = l16 * 128 + ((quad ^ (l16 & 7)) * 16);
    const int koff1 = l16 * 128 + (((quad + 4) ^ (l16 & 7)) * 16);
    const int vbase = l16 * 128 + (quad & 1) * 8;
    int vx[4];
    #pragma unroll
    for (int sj = 0; sj < 4; ++sj)
        vx[sj] = ((sj * 2 + (quad >> 1)) ^ (l16 & 7)) * 16;

    const f32x4 zero4 = {0.f, 0.f, 0.f, 0.f};

    const int base0 = qt * 128 + wv * 16;   // strip 0: wave's first 16 q-rows
    const int base1 = base0 + 64;           // strip 1: wave's second 16 q-rows

    auto stage = [&](int t) {
        const char* kg = kpb + (size_t)t * 8192;   // K tile: row stride 128B
        const char* vg = vpb + (size_t)t * 128;    // V tile: row stride 4096B
        char* kd = kbuf[t & 1];
        char* vd = vbuf[t & 1];
        #pragma unroll
        for (int c = 0; c < 2; ++c) {
            const int gr = wv * 16 + c * 8;        // wave-uniform group row
            gload_lds16(kg + gr * 128 + k_src, kd + gr * 128);
            gload_lds16(vg + gr * 4096 + v_src, vd + gr * 128);
        }
    };

    stage(0);

    // Q B-fragments for both strips: lane holds Q[base+l16][ks*32 + quad*8 + j]
    const float* qr0 = qp + (size_t)(base0 + l16) * DMODEL + quad * 8;
    const float* qr1 = qp + (size_t)(base1 + l16) * DMODEL + quad * 8;
    const F8 aq00 = pack8_f32(qr0);
    const F8 aq01 = pack8_f32(qr0 + 32);
    const F8 aq10 = pack8_f32(qr1);
    const F8 aq11 = pack8_f32(qr1 + 32);

    f32x4 o0[4], o1[4];
    float lp0 = 0.f, lp1 = 0.f;
    float dbq0[4], dbq1[4];
    #pragma unroll
    for (int nt = 0; nt < 4; ++nt) { o0[nt] = zero4; o1[nt] = zero4; }
    #pragma unroll
    for (int sj = 0; sj < 4; ++sj) {
        dbq0[sj] = (float)(sj * 16 + quad * 4 - base0 - l16) * bslope2;
        dbq1[sj] = (float)(sj * 16 + quad * 4 - base1 - l16) * bslope2;
    }

    __syncthreads();

    for (int t = 0; t <= sx2; ++t) {
        if (t < sx2) stage(t + 1);
        const char* kb = kbuf[t & 1];
        const char* vb = vbuf[t & 1];

        // K A-fragments from swizzled LDS (8 x ds_read_b128), shared by strips
        F8 kA[4][2];
        #pragma unroll
        for (int sj = 0; sj < 4; ++sj) {
            kA[sj][0].u = *(const uint4*)(kb + sj * 2048 + koff0);
            kA[sj][1].u = *(const uint4*)(kb + sj * 2048 + koff1);
        }

        const bool run0 = (t < sx2);   // strip 0 has no work on the last tile

        // S^T = K Q^T : A=K, B=Q. D[s_local=quad*4+r][t_local=l16]
        f32x4 sT0[4], sT1[4];
        __builtin_amdgcn_s_setprio(1);
        if (run0) {
            #pragma unroll
            for (int sj = 0; sj < 4; ++sj) {
                f32x4 acc = zero4;
                acc = __builtin_amdgcn_mfma_f32_16x16x32_f16(kA[sj][0].v, aq00.v, acc, 0, 0, 0);
                acc = __builtin_amdgcn_mfma_f32_16x16x32_f16(kA[sj][1].v, aq01.v, acc, 0, 0, 0);
                sT0[sj] = acc;
            }
        }
        #pragma unroll
        for (int sj = 0; sj < 4; ++sj) {
            f32x4 acc = zero4;
            acc = __builtin_amdgcn_mfma_f32_16x16x32_f16(kA[sj][0].v, aq10.v, acc, 0, 0, 0);
            acc = __builtin_amdgcn_mfma_f32_16x16x32_f16(kA[sj][1].v, aq11.v, acc, 0, 0, 0);
            sT1[sj] = acc;
        }
        __builtin_amdgcn_s_setprio(0);

        // V B-fragments (16x16x16): V[sj*16+quad*4+j][nt*16+l16], 16 x ds_read_b64
        F4 vf[4][4];
        #pragma unroll
        for (int nt = 0; nt < 4; ++nt)
            #pragma unroll
            for (int sj = 0; sj < 4; ++sj)
                vf[nt][sj].u = *(const uint2*)(vb + nt * 2048 + vbase + vx[sj]);

        // ---- strip 0 ----
        if (run0) {
            const bool masked = (t == sx2 - 1);
            F4 pP[4];
            #pragma unroll
            for (int sj = 0; sj < 4; ++sj) {
                const float db = dbq0[sj];
                float p0 = EXP2F(fmaf(sT0[sj][0], sscale2, db));
                float p1 = EXP2F(fmaf(sT0[sj][1], sscale2, db + rb1));
                float p2 = EXP2F(fmaf(sT0[sj][2], sscale2, db + rb2));
                float p3 = EXP2F(fmaf(sT0[sj][3], sscale2, db + rb3));
                if (masked) {
                    const int di = t * 64 + sj * 16 + quad * 4 - base0 - l16;
                    if (di + 0 > 0) p0 = 0.f;
                    if (di + 1 > 0) p1 = 0.f;
                    if (di + 2 > 0) p2 = 0.f;
                    if (di + 3 > 0) p3 = 0.f;
                }
                lp0 += (p0 + p1) + (p2 + p3);
                pP[sj].h[0] = pk(p0, p1);
                pP[sj].h[1] = pk(p2, p3);
                dbq0[sj] = db + step64;
            }
            __builtin_amdgcn_s_setprio(1);
            #pragma unroll
            for (int nt = 0; nt < 4; ++nt)
                #pragma unroll
                for (int sj = 0; sj < 4; ++sj)
                    o0[nt] = __builtin_amdgcn_mfma_f32_16x16x16f16(
                        pP[sj].v, vf[nt][sj].v, o0[nt], 0, 0, 0);
            __builtin_amdgcn_s_setprio(0);
        }

        // ---- strip 1 ----
        {
            const bool masked = (t == sx2);
            F4 pP[4];
            #pragma unroll
            for (int sj = 0; sj < 4; ++sj) {
                const float db = dbq1[sj];
                float p0 = EXP2F(fmaf(sT1[sj][0], sscale2, db));
                float p1 = EXP2F(fmaf(sT1[sj][1], sscale2, db + rb1));
                float p2 = EXP2F(fmaf(sT1[sj][2], sscale2, db + rb2));
                float p3 = EXP2F(fmaf(sT1[sj][3], sscale2, db + rb3));
                if (masked) {
                    const int di = t * 64 + sj * 16 + quad * 4 - base1 - l16;
                    if (di + 0 > 0) p0 = 0.f;
                    if (di + 1 > 0) p1 = 0.f;
                    if (di + 2 > 0) p2 = 0.f;
                    if (di + 3 > 0) p3 = 0.f;
                }
                lp1 += (p0 + p1) + (p2 + p3);
                pP[sj].h[0] = pk(p0, p1);
                pP[sj].h[1] = pk(p2, p3);
                dbq1[sj] = db + step64;
            }
            __builtin_amdgcn_s_setprio(1);
            #pragma unroll
            for (int nt = 0; nt < 4; ++nt)
                #pragma unroll
                for (int sj = 0; sj < 4; ++sj)
                    o1[nt] = __builtin_amdgcn_mfma_f32_16x16x16f16(
                        pP[sj].v, vf[nt][sj].v, o1[nt], 0, 0, 0);
            __builtin_amdgcn_s_setprio(0);
        }

        __syncthreads();   // drains staged loads + all buf reads
    }

    // ---- epilogue: l lives per-lane at row t=l16; reduce across quads ----
    #pragma unroll
    for (int m = 0; m < 2; ++m) {
        const float lpm  = m ? lp1 : lp0;
        const f32x4* om  = m ? o1 : o0;
        const int base_m = m ? base1 : base0;
        float ls = lpm;
        ls += __shfl_xor(ls, 16);
        ls += __shfl_xor(ls, 32);
        float lr[4];
        #pragma unroll
        for (int r = 0; r < 4; ++r)
            lr[r] = __shfl(ls, quad * 4 + r);   // l for this lane's output rows
        #pragma unroll
        for (int nt = 0; nt < 4; ++nt)
            #pragma unroll
            for (int r = 0; r < 4; ++r) {
                const int trow = base_m + quad * 4 + r;
                O[((size_t)b * TSEQ + trow) * DMODEL + h * DHEAD + nt * 16 + l16] =
                    om[nt][r] / lr[r];
            }
    }
}

extern "C" void kernel_launch(void* const* d_in, const int* in_sizes, int n_in,
                              void* d_out, int out_size, void* d_ws, size_t ws_size,
                              hipStream_t stream) {
    const float* q = (const float*)d_in[0];
    const float* k = (const float*)d_in[1];
    const float* v = (const float*)d_in[2];
    float* out = (float*)d_out;

    _Float16* Kh = (_Float16*)d_ws;                                  // 8.4 MB
    _Float16* Vh = Kh + (size_t)BATCH * N_HEAD * TSEQ * DHEAD;       // 8.4 MB

    prep<<<dim3(TSEQ / 64, BATCH * N_HEAD), 256, 0, stream>>>(k, v, Kh, Vh);
    alibi_attn<<<dim3(BATCH * N_HEAD, 16), 256, 0, stream>>>(q, Kh, Vh, out);
}

// Round 4
// 137.085 us; speedup vs baseline: 1.0313x; 1.0313x over previous
//
#include <hip/hip_runtime.h>

#define N_HEAD 16
#define DHEAD 64
#define TSEQ 2048
#define DMODEL 1024
#define BATCH 2

typedef _Float16 f16x8 __attribute__((ext_vector_type(8)));
typedef _Float16 f16x4 __attribute__((ext_vector_type(4)));
typedef _Float16 f16x2 __attribute__((ext_vector_type(2)));
typedef __fp16 fp16x2 __attribute__((ext_vector_type(2)));
typedef float f32x4 __attribute__((ext_vector_type(4)));

union F8 { f16x8 v; uint4 u; f16x2 h[4]; };
union F4 { f16x4 v; uint2 u; f16x2 h[2]; };

#if __has_builtin(__builtin_amdgcn_exp2f)
#define EXP2F(x) __builtin_amdgcn_exp2f(x)
#else
#define EXP2F(x) exp2f(x)
#endif

// async global->LDS: HW writes lane i's 16B at (wave-uniform lds base) + i*16
__device__ __forceinline__ void gload_lds16(const void* g, void* l) {
    __builtin_amdgcn_global_load_lds(
        (const __attribute__((address_space(1))) void*)g,
        (__attribute__((address_space(3))) void*)l, 16, 0, 0);
}

// v_cvt_pkrtz_f16_f32: pack two fp32 -> two f16 (RTZ)
__device__ __forceinline__ f16x2 pk(float a, float b) {
    union { fp16x2 i; f16x2 o; } c;
    c.i = __builtin_amdgcn_cvt_pkrtz(a, b);
    return c.o;
}

__device__ __forceinline__ F8 pack8_f32(const float* p) {
    const float4 a = *(const float4*)p;
    const float4 b = *(const float4*)(p + 4);
    F8 r;
    r.h[0] = pk(a.x, a.y); r.h[1] = pk(a.z, a.w);
    r.h[2] = pk(b.x, b.y); r.h[3] = pk(b.z, b.w);
    return r;
}

// Prepass: K [B,S,DMODEL] f32 -> Kh [BH,S,64] f16 (head-major)
//          V [B,S,DMODEL] f32 -> Vh [BH,64,S] f16 (transposed)
__global__ __launch_bounds__(256) void prep(const float* __restrict__ K,
                                            const float* __restrict__ V,
                                            _Float16* __restrict__ Kh,
                                            _Float16* __restrict__ Vh)
{
    __shared__ float tl[64][67];
    const int bh = blockIdx.y, b = bh >> 4, h = bh & 15;
    const int s0 = blockIdx.x * 64;
    const int t = threadIdx.x;
    const int r16 = t >> 4, c4 = (t & 15) * 4;
    #pragma unroll
    for (int pass = 0; pass < 4; ++pass) {
        const int row = pass * 16 + r16;
        const size_t goff = ((size_t)(b * TSEQ + s0 + row)) * DMODEL + h * DHEAD + c4;
        const float4 fk = *(const float4*)(K + goff);
        F4 ok;
        ok.h[0] = pk(fk.x, fk.y);
        ok.h[1] = pk(fk.z, fk.w);
        *(uint2*)(Kh + (((size_t)bh * TSEQ + s0 + row) << 6) + c4) = ok.u;
        const float4 fv = *(const float4*)(V + goff);
        tl[row][c4 + 0] = fv.x; tl[row][c4 + 1] = fv.y;
        tl[row][c4 + 2] = fv.z; tl[row][c4 + 3] = fv.w;
    }
    __syncthreads();
    const int d = t >> 2, sc = (t & 3) * 16;
    F8 p0, p1;
    #pragma unroll
    for (int j = 0; j < 4; ++j) p0.h[j] = pk(tl[sc + 2 * j][d], tl[sc + 2 * j + 1][d]);
    #pragma unroll
    for (int j = 0; j < 4; ++j) p1.h[j] = pk(tl[sc + 8 + 2 * j][d], tl[sc + 9 + 2 * j][d]);
    _Float16* vo = Vh + ((size_t)bh * DHEAD + d) * TSEQ + s0 + sc;
    *(uint4*)vo = p0.u;
    *(uint4*)(vo + 8) = p1.u;
}

// 2-wave blocks, 2 strips/wave: 64 q-rows per block read each K/V tile with
// only 2 waves -> LDS bytes per unit work halved vs the 4-wave version
// (LDS is the saturated pipe: ~1700 cyc per 64x64 unit, residency-invariant).
// 1024 blocks x 2 waves = 4 blocks/CU ALL resident (128KB LDS, 8 waves/CU);
// sx mapping makes per-CU total iters exactly 66 for every CU.
__global__ __launch_bounds__(128, 2) void alibi_attn(
    const float* __restrict__ Q, const _Float16* __restrict__ Kh,
    const _Float16* __restrict__ Vh, float* __restrict__ O)
{
    // double-buffered 64x64 f16 KV tiles, XOR-swizzled 16B chunks:
    // data chunk (row, c) lives at LDS slot (row, c ^ (row&7))
    __shared__ __align__(16) char kbuf[2][8192];
    __shared__ __align__(16) char vbuf[2][8192];

    const int wv   = threadIdx.x >> 6;   // 0..1
    const int lane = threadIdx.x & 63;
    const int quad = lane >> 4;
    const int l16  = lane & 15;

    const int bh = blockIdx.x;
    const int b  = bh >> 4, h = bh & 15;
    // CU n hosts by = {j, j+8, j+16, j+24} (strict round-robin of 1024 blocks,
    // all co-resident). sx = {j, 15-j, 16+j, 31-j} -> per-CU iters = 66 const.
    const int by = blockIdx.y;
    const int g = by >> 3, j = by & 7;
    const int sx = (g == 0) ? j : (g == 1) ? (15 - j) : (g == 2) ? (16 + j) : (31 - j);

    const float LOG2E   = 1.44269504088896f;
    const float slope   = exp2f(-0.5f * (float)(h + 1));
    const float bslope2 = slope * LOG2E;
    const float sscale2 = 0.125f * LOG2E;
    const float step64  = 64.0f * bslope2;
    const float rb1 = bslope2, rb2 = 2.f * bslope2, rb3 = 3.f * bslope2;

    const float* qp  = Q + (size_t)b * TSEQ * DMODEL + (size_t)h * DHEAD;
    const char*  kpb = (const char*)(Kh + (size_t)bh * TSEQ * DHEAD);
    const char*  vpb = (const char*)(Vh + (size_t)bh * DHEAD * TSEQ);

    // staging constants: lane i -> LDS slot (row gr + i/8, chunk i&7);
    // source chunk = (i&7) ^ (i/8) so slot sc holds data chunk sc^(row&7)
    const int st_r  = lane >> 3;
    const int k_src = st_r * 128  + (((lane & 7) ^ st_r) * 16);
    const int v_src = st_r * 4096 + (((lane & 7) ^ st_r) * 16);

    // fragment LDS offsets (loop-invariant)
    const int koff0 = l16 * 128 + ((quad ^ (l16 & 7)) * 16);
    const int koff1 = l16 * 128 + (((quad + 4) ^ (l16 & 7)) * 16);
    const int vbase = l16 * 128 + (quad & 1) * 8;
    int vx[4];
    #pragma unroll
    for (int sj = 0; sj < 4; ++sj)
        vx[sj] = ((sj * 2 + (quad >> 1)) ^ (l16 & 7)) * 16;

    const f32x4 zero4 = {0.f, 0.f, 0.f, 0.f};

    const int base0 = sx * 64 + wv * 16;    // strip 0: rows [base0, base0+16)
    const int base1 = base0 + 32;           // strip 1: rows [base1, base1+16)

    auto stage = [&](int t) {
        const char* kg = kpb + (size_t)t * 8192;   // K tile: row stride 128B
        const char* vg = vpb + (size_t)t * 128;    // V tile: row stride 4096B
        char* kd = kbuf[t & 1];
        char* vd = vbuf[t & 1];
        #pragma unroll
        for (int c = 0; c < 4; ++c) {
            const int gr = wv * 32 + c * 8;        // wave-uniform group row
            gload_lds16(kg + gr * 128 + k_src, kd + gr * 128);
            gload_lds16(vg + gr * 4096 + v_src, vd + gr * 128);
        }
    };

    stage(0);

    // Q B-fragments for both strips: lane holds Q[base+l16][ks*32 + quad*8 + j]
    const float* qr0 = qp + (size_t)(base0 + l16) * DMODEL + quad * 8;
    const float* qr1 = qp + (size_t)(base1 + l16) * DMODEL + quad * 8;
    const F8 aq00 = pack8_f32(qr0);
    const F8 aq01 = pack8_f32(qr0 + 32);
    const F8 aq10 = pack8_f32(qr1);
    const F8 aq11 = pack8_f32(qr1 + 32);

    f32x4 o0[4], o1[4];
    float lp0 = 0.f, lp1 = 0.f;
    float dbq0[4], dbq1[4];
    #pragma unroll
    for (int nt = 0; nt < 4; ++nt) { o0[nt] = zero4; o1[nt] = zero4; }
    #pragma unroll
    for (int sj = 0; sj < 4; ++sj) {
        dbq0[sj] = (float)(sj * 16 + quad * 4 - base0 - l16) * bslope2;
        dbq1[sj] = (float)(sj * 16 + quad * 4 - base1 - l16) * bslope2;
    }

    __syncthreads();

    for (int t = 0; t <= sx; ++t) {
        if (t < sx) stage(t + 1);
        const char* kb = kbuf[t & 1];
        const char* vb = vbuf[t & 1];

        // K A-fragments from swizzled LDS (8 x ds_read_b128), shared by strips
        F8 kA[4][2];
        #pragma unroll
        for (int sj = 0; sj < 4; ++sj) {
            kA[sj][0].u = *(const uint4*)(kb + sj * 2048 + koff0);
            kA[sj][1].u = *(const uint4*)(kb + sj * 2048 + koff1);
        }

        // S^T = K Q^T : A=K, B=Q. D[s_local=quad*4+r][t_local=l16]
        f32x4 sT0[4], sT1[4];
        __builtin_amdgcn_s_setprio(1);
        #pragma unroll
        for (int sj = 0; sj < 4; ++sj) {
            f32x4 acc = zero4;
            acc = __builtin_amdgcn_mfma_f32_16x16x32_f16(kA[sj][0].v, aq00.v, acc, 0, 0, 0);
            acc = __builtin_amdgcn_mfma_f32_16x16x32_f16(kA[sj][1].v, aq01.v, acc, 0, 0, 0);
            sT0[sj] = acc;
        }
        #pragma unroll
        for (int sj = 0; sj < 4; ++sj) {
            f32x4 acc = zero4;
            acc = __builtin_amdgcn_mfma_f32_16x16x32_f16(kA[sj][0].v, aq10.v, acc, 0, 0, 0);
            acc = __builtin_amdgcn_mfma_f32_16x16x32_f16(kA[sj][1].v, aq11.v, acc, 0, 0, 0);
            sT1[sj] = acc;
        }
        __builtin_amdgcn_s_setprio(0);

        // V B-fragments (16x16x16): V[sj*16+quad*4+j][nt*16+l16], 16 x ds_read_b64
        F4 vf[4][4];
        #pragma unroll
        for (int nt = 0; nt < 4; ++nt)
            #pragma unroll
            for (int sj = 0; sj < 4; ++sj)
                vf[nt][sj].u = *(const uint2*)(vb + nt * 2048 + vbase + vx[sj]);

        // exp (exp2 domain; no running max: scores/8 ~ N(0,1), bias <= 0,
        // args bounded << 128 -> overflow-safe), pack to f16 A-frags in-reg.
        // Mask only the diagonal tile: for t<sx, all s <= t*64+63 < base rows.
        const bool masked = (t == sx);
        F4 pP0[4], pP1[4];
        #pragma unroll
        for (int sj = 0; sj < 4; ++sj) {
            const float db = dbq0[sj];
            float p0 = EXP2F(fmaf(sT0[sj][0], sscale2, db));
            float p1 = EXP2F(fmaf(sT0[sj][1], sscale2, db + rb1));
            float p2 = EXP2F(fmaf(sT0[sj][2], sscale2, db + rb2));
            float p3 = EXP2F(fmaf(sT0[sj][3], sscale2, db + rb3));
            if (masked) {
                const int di = t * 64 + sj * 16 + quad * 4 - base0 - l16;
                if (di + 0 > 0) p0 = 0.f;
                if (di + 1 > 0) p1 = 0.f;
                if (di + 2 > 0) p2 = 0.f;
                if (di + 3 > 0) p3 = 0.f;
            }
            lp0 += (p0 + p1) + (p2 + p3);
            pP0[sj].h[0] = pk(p0, p1);
            pP0[sj].h[1] = pk(p2, p3);
            dbq0[sj] = db + step64;
        }
        #pragma unroll
        for (int sj = 0; sj < 4; ++sj) {
            const float db = dbq1[sj];
            float p0 = EXP2F(fmaf(sT1[sj][0], sscale2, db));
            float p1 = EXP2F(fmaf(sT1[sj][1], sscale2, db + rb1));
            float p2 = EXP2F(fmaf(sT1[sj][2], sscale2, db + rb2));
            float p3 = EXP2F(fmaf(sT1[sj][3], sscale2, db + rb3));
            if (masked) {
                const int di = t * 64 + sj * 16 + quad * 4 - base1 - l16;
                if (di + 0 > 0) p0 = 0.f;
                if (di + 1 > 0) p1 = 0.f;
                if (di + 2 > 0) p2 = 0.f;
                if (di + 3 > 0) p3 = 0.f;
            }
            lp1 += (p0 + p1) + (p2 + p3);
            pP1[sj].h[0] = pk(p0, p1);
            pP1[sj].h[1] = pk(p2, p3);
            dbq1[sj] = db + step64;
        }

        // O += P V : P already in A-layout (k=quad*4+j == s_local), 16x16x16
        __builtin_amdgcn_s_setprio(1);
        #pragma unroll
        for (int nt = 0; nt < 4; ++nt)
            #pragma unroll
            for (int sj = 0; sj < 4; ++sj)
                o0[nt] = __builtin_amdgcn_mfma_f32_16x16x16f16(
                    pP0[sj].v, vf[nt][sj].v, o0[nt], 0, 0, 0);
        #pragma unroll
        for (int nt = 0; nt < 4; ++nt)
            #pragma unroll
            for (int sj = 0; sj < 4; ++sj)
                o1[nt] = __builtin_amdgcn_mfma_f32_16x16x16f16(
                    pP1[sj].v, vf[nt][sj].v, o1[nt], 0, 0, 0);
        __builtin_amdgcn_s_setprio(0);

        __syncthreads();   // drains staged loads + all buf reads
    }

    // ---- epilogue: l lives per-lane at row t=l16; reduce across quads ----
    #pragma unroll
    for (int m = 0; m < 2; ++m) {
        const float lpm  = m ? lp1 : lp0;
        const f32x4* om  = m ? o1 : o0;
        const int base_m = m ? base1 : base0;
        float ls = lpm;
        ls += __shfl_xor(ls, 16);
        ls += __shfl_xor(ls, 32);
        float lr[4];
        #pragma unroll
        for (int r = 0; r < 4; ++r)
            lr[r] = __shfl(ls, quad * 4 + r);   // l for this lane's output rows
        #pragma unroll
        for (int nt = 0; nt < 4; ++nt)
            #pragma unroll
            for (int r = 0; r < 4; ++r) {
                const int trow = base_m + quad * 4 + r;
                O[((size_t)b * TSEQ + trow) * DMODEL + h * DHEAD + nt * 16 + l16] =
                    om[nt][r] / lr[r];
            }
    }
}

extern "C" void kernel_launch(void* const* d_in, const int* in_sizes, int n_in,
                              void* d_out, int out_size, void* d_ws, size_t ws_size,
                              hipStream_t stream) {
    const float* q = (const float*)d_in[0];
    const float* k = (const float*)d_in[1];
    const float* v = (const float*)d_in[2];
    float* out = (float*)d_out;

    _Float16* Kh = (_Float16*)d_ws;                                  // 8.4 MB
    _Float16* Vh = Kh + (size_t)BATCH * N_HEAD * TSEQ * DHEAD;       // 8.4 MB

    prep<<<dim3(TSEQ / 64, BATCH * N_HEAD), 256, 0, stream>>>(k, v, Kh, Vh);
    alibi_attn<<<dim3(BATCH * N_HEAD, 32), 128, 0, stream>>>(q, Kh, Vh, out);
}

// Round 5
// 127.922 us; speedup vs baseline: 1.1051x; 1.0716x over previous
//
#include <hip/hip_runtime.h>

#define N_HEAD 16
#define DHEAD 64
#define TSEQ 2048
#define DMODEL 1024
#define BATCH 2

typedef _Float16 f16x8 __attribute__((ext_vector_type(8)));
typedef _Float16 f16x4 __attribute__((ext_vector_type(4)));
typedef _Float16 f16x2 __attribute__((ext_vector_type(2)));
typedef __fp16 fp16x2 __attribute__((ext_vector_type(2)));
typedef float f32x4 __attribute__((ext_vector_type(4)));

union F8 { f16x8 v; uint4 u; f16x2 h[4]; };
union F4 { f16x4 v; uint2 u; f16x2 h[2]; };

#if __has_builtin(__builtin_amdgcn_exp2f)
#define EXP2F(x) __builtin_amdgcn_exp2f(x)
#else
#define EXP2F(x) exp2f(x)
#endif

// async global->LDS: HW writes lane i's 16B at (wave-uniform lds base) + i*16
__device__ __forceinline__ void gload_lds16(const void* g, void* l) {
    __builtin_amdgcn_global_load_lds(
        (const __attribute__((address_space(1))) void*)g,
        (__attribute__((address_space(3))) void*)l, 16, 0, 0);
}

// v_cvt_pkrtz_f16_f32: pack two fp32 -> two f16 (RTZ)
__device__ __forceinline__ f16x2 pk(float a, float b) {
    union { fp16x2 i; f16x2 o; } c;
    c.i = __builtin_amdgcn_cvt_pkrtz(a, b);
    return c.o;
}

__device__ __forceinline__ F8 pack8_f32(const float* p) {
    const float4 a = *(const float4*)p;
    const float4 b = *(const float4*)(p + 4);
    F8 r;
    r.h[0] = pk(a.x, a.y); r.h[1] = pk(a.z, a.w);
    r.h[2] = pk(b.x, b.y); r.h[3] = pk(b.z, b.w);
    return r;
}

// Prepass: K [B,S,DMODEL] f32 -> Kh [BH,S,64] f16 (head-major)
//          V [B,S,DMODEL] f32 -> Vh [BH,64,S] f16 (transposed)
__global__ __launch_bounds__(256) void prep(const float* __restrict__ K,
                                            const float* __restrict__ V,
                                            _Float16* __restrict__ Kh,
                                            _Float16* __restrict__ Vh)
{
    __shared__ float tl[64][67];
    const int bh = blockIdx.y, b = bh >> 4, h = bh & 15;
    const int s0 = blockIdx.x * 64;
    const int t = threadIdx.x;
    const int r16 = t >> 4, c4 = (t & 15) * 4;
    #pragma unroll
    for (int pass = 0; pass < 4; ++pass) {
        const int row = pass * 16 + r16;
        const size_t goff = ((size_t)(b * TSEQ + s0 + row)) * DMODEL + h * DHEAD + c4;
        const float4 fk = *(const float4*)(K + goff);
        F4 ok;
        ok.h[0] = pk(fk.x, fk.y);
        ok.h[1] = pk(fk.z, fk.w);
        *(uint2*)(Kh + (((size_t)bh * TSEQ + s0 + row) << 6) + c4) = ok.u;
        const float4 fv = *(const float4*)(V + goff);
        tl[row][c4 + 0] = fv.x; tl[row][c4 + 1] = fv.y;
        tl[row][c4 + 2] = fv.z; tl[row][c4 + 3] = fv.w;
    }
    __syncthreads();
    const int d = t >> 2, sc = (t & 3) * 16;
    F8 p0, p1;
    #pragma unroll
    for (int j = 0; j < 4; ++j) p0.h[j] = pk(tl[sc + 2 * j][d], tl[sc + 2 * j + 1][d]);
    #pragma unroll
    for (int j = 0; j < 4; ++j) p1.h[j] = pk(tl[sc + 8 + 2 * j][d], tl[sc + 9 + 2 * j][d]);
    _Float16* vo = Vh + ((size_t)bh * DHEAD + d) * TSEQ + s0 + sc;
    *(uint4*)vo = p0.u;
    *(uint4*)(vo + 8) = p1.u;
}

// s-split: wave w owns s-rows [16w,16w+16) of each K/V tile vs ALL 64 q-rows.
// Per-wave per-iter: 2 ds_read_b128 + 4 ds_read_b64 (vs 24 ops q-split) ->
// 4x less LDS on the per-iteration chain (the measured residency-invariant
// bottleneck, ~1650 cyc/unit). O/l are s-partial; cross-wave LDS reduce once
// per block in the epilogue.
__global__ __launch_bounds__(256, 2) void alibi_attn(
    const float* __restrict__ Q, const _Float16* __restrict__ Kh,
    const _Float16* __restrict__ Vh, float* __restrict__ O)
{
    // 32KB: main loop = double-buffered K (2x8KB) + V (2x8KB), XOR-swizzled
    // 16B chunks (data chunk c of row r at slot c^(r&7)). Epilogue reuses all
    // 32KB for the cross-wave O reduction.
    __shared__ __align__(16) char smem[32768];
    char* kb0 = smem;            // kbuf[2][8192]
    char* vb0 = smem + 16384;    // vbuf[2][8192]

    const int wv   = threadIdx.x >> 6;   // wave id = s-slice owner
    const int lane = threadIdx.x & 63;
    const int quad = lane >> 4;
    const int l16  = lane & 15;

    const int bh = blockIdx.x;
    const int b  = bh >> 4, h = bh & 15;
    // heavy q-tiles first; 1024 variable blocks backfill (r1-proven packing)
    const int qt = 31 - (int)blockIdx.y;
    const int sx = qt;

    const float LOG2E   = 1.44269504088896f;
    const float slope   = exp2f(-0.5f * (float)(h + 1));
    const float bslope2 = slope * LOG2E;
    const float sscale2 = 0.125f * LOG2E;
    const float step64  = 64.0f * bslope2;
    const float rb1 = bslope2, rb2 = 2.f * bslope2, rb3 = 3.f * bslope2;

    const float* qp  = Q + (size_t)b * TSEQ * DMODEL + (size_t)h * DHEAD;
    const char*  kpb = (const char*)(Kh + (size_t)bh * TSEQ * DHEAD);
    const char*  vpb = (const char*)(Vh + (size_t)bh * DHEAD * TSEQ);

    // staging constants (unchanged): lane i -> slot (row gr+i/8, chunk i&7),
    // source chunk = (i&7)^(i/8) so slot sc holds data chunk sc^(row&7)
    const int st_r  = lane >> 3;
    const int k_src = st_r * 128  + (((lane & 7) ^ st_r) * 16);
    const int v_src = st_r * 4096 + (((lane & 7) ^ st_r) * 16);

    // fragment LDS offsets: wave reads only its slice sj == wv
    const int koff0 = l16 * 128 + ((quad ^ (l16 & 7)) * 16);
    const int koff1 = l16 * 128 + (((quad + 4) ^ (l16 & 7)) * 16);
    const int vbase = l16 * 128 + (quad & 1) * 8;
    const int vxw   = ((wv * 2 + (quad >> 1)) ^ (l16 & 7)) * 16;

    const f32x4 zero4 = {0.f, 0.f, 0.f, 0.f};

    auto stage = [&](int t) {
        const char* kg = kpb + (size_t)t * 8192;   // K tile: row stride 128B
        const char* vg = vpb + (size_t)t * 128;    // V tile: row stride 4096B
        char* kd = kb0 + (t & 1) * 8192;
        char* vd = vb0 + (t & 1) * 8192;
        #pragma unroll
        for (int c = 0; c < 2; ++c) {
            const int gr = wv * 16 + c * 8;        // wave-uniform group row
            gload_lds16(kg + gr * 128 + k_src, kd + gr * 128);
            gload_lds16(vg + gr * 4096 + v_src, vd + gr * 128);
        }
    };

    stage(0);

    // Q B-fragments for all 4 q-blocks: lane holds Q[qt*64+qb*16+l16][ks*32+quad*8+j]
    F8 aq[4][2];
    #pragma unroll
    for (int qb = 0; qb < 4; ++qb) {
        const float* qr = qp + (size_t)(qt * 64 + qb * 16 + l16) * DMODEL + quad * 8;
        aq[qb][0] = pack8_f32(qr);
        aq[qb][1] = pack8_f32(qr + 32);
    }

    f32x4 o[4][4];                 // o[qb][nt]: partial O over wave's s-slice
    float lp[4];                   // partial softmax denom per q-block
    float dbq[4];
    #pragma unroll
    for (int qb = 0; qb < 4; ++qb) {
        #pragma unroll
        for (int nt = 0; nt < 4; ++nt) o[qb][nt] = zero4;
        lp[qb] = 0.f;
        dbq[qb] = (float)(wv * 16 + quad * 4 - qt * 64 - qb * 16 - l16) * bslope2;
    }

    __syncthreads();

    for (int t = 0; t <= sx; ++t) {
        if (t < sx) stage(t + 1);
        const char* kb = kb0 + (t & 1) * 8192;
        const char* vb = vb0 + (t & 1) * 8192;

        // K A-fragment: only this wave's 16 s-rows (2 x ds_read_b128)
        F8 kA0, kA1;
        kA0.u = *(const uint4*)(kb + wv * 2048 + koff0);
        kA1.u = *(const uint4*)(kb + wv * 2048 + koff1);

        // V B-fragments: V[wv*16+quad*4+j][nt*16+l16] (4 x ds_read_b64)
        F4 vf[4];
        #pragma unroll
        for (int nt = 0; nt < 4; ++nt)
            vf[nt].u = *(const uint2*)(vb + nt * 2048 + vbase + vxw);

        // S^T = K Q^T per q-block: D[s_local=quad*4+r][q_local=l16]
        f32x4 sT[4];
        __builtin_amdgcn_s_setprio(1);
        #pragma unroll
        for (int qb = 0; qb < 4; ++qb) {
            f32x4 acc = zero4;
            acc = __builtin_amdgcn_mfma_f32_16x16x32_f16(kA0.v, aq[qb][0].v, acc, 0, 0, 0);
            acc = __builtin_amdgcn_mfma_f32_16x16x32_f16(kA1.v, aq[qb][1].v, acc, 0, 0, 0);
            sT[qb] = acc;
        }
        __builtin_amdgcn_s_setprio(0);

        // exp (exp2 domain; no running max: scores/8 ~ N(0,1), bias <= 0,
        // args bounded << 128 -> overflow-safe), pack to f16 A-frags in-reg.
        // t < sx: all s <= t*64+63 < sx*64 <= q -> mask only diagonal tile.
        const bool masked = (t == sx);
        F4 pP[4];
        #pragma unroll
        for (int qb = 0; qb < 4; ++qb) {
            const float db = dbq[qb];
            float p0 = EXP2F(fmaf(sT[qb][0], sscale2, db));
            float p1 = EXP2F(fmaf(sT[qb][1], sscale2, db + rb1));
            float p2 = EXP2F(fmaf(sT[qb][2], sscale2, db + rb2));
            float p3 = EXP2F(fmaf(sT[qb][3], sscale2, db + rb3));
            if (masked) {
                const int di = t * 64 + wv * 16 + quad * 4 - (qt * 64 + qb * 16 + l16);
                if (di + 0 > 0) p0 = 0.f;
                if (di + 1 > 0) p1 = 0.f;
                if (di + 2 > 0) p2 = 0.f;
                if (di + 3 > 0) p3 = 0.f;
            }
            lp[qb] += (p0 + p1) + (p2 + p3);
            pP[qb].h[0] = pk(p0, p1);
            pP[qb].h[1] = pk(p2, p3);
            dbq[qb] = db + step64;
        }

        // O_partial += P V over this wave's 16 s (k=16): 16 x 16x16x16
        __builtin_amdgcn_s_setprio(1);
        #pragma unroll
        for (int qb = 0; qb < 4; ++qb)
            #pragma unroll
            for (int nt = 0; nt < 4; ++nt)
                o[qb][nt] = __builtin_amdgcn_mfma_f32_16x16x16f16(
                    pP[qb].v, vf[nt].v, o[qb][nt], 0, 0, 0);
        __builtin_amdgcn_s_setprio(0);

        __syncthreads();   // drains staged loads + all buf reads
    }

    // ================= epilogue: cross-wave s-reduction =================
    // 1) softmax denominators: quad-reduce, stage per-wave partials in LDS
    float lsq[4];
    #pragma unroll
    for (int qb = 0; qb < 4; ++qb) {
        float ls = lp[qb];
        ls += __shfl_xor(ls, 16);
        ls += __shfl_xor(ls, 32);
        lsq[qb] = ls;                       // partial l for q = qb*16+l16
    }
    float* lred = (float*)smem;             // [4 w][4 qb * 16 q] = 1KB
    if (quad == 0) {
        #pragma unroll
        for (int qb = 0; qb < 4; ++qb)
            lred[wv * 64 + qb * 16 + l16] = lsq[qb];
    }
    __syncthreads();

    // epilogue thread mapping: t -> (qb2, qrow, chunk-of-8-d)
    const int tt   = threadIdx.x;
    const int qb2  = tt >> 7;               // 0..1
    const int qrow = (tt >> 3) & 15;        // 0..15
    const int chnk = tt & 7;                // 0..7 (d8 = chnk*8)
    float lA = 0.f, lB = 0.f;
    #pragma unroll
    for (int w = 0; w < 4; ++w) {
        lA += lred[w * 64 + qb2 * 16 + qrow];
        lB += lred[w * 64 + (2 + qb2) * 16 + qrow];
    }
    __syncthreads();                        // lred reads done before overwrite

    // 2) O reduction in two rounds (qb {0,1} then {2,3}); 32KB staging:
    // part[w][qb2][q=16][d=64] f32, d-chunk XOR-swizzled by (q&7)
    float* part = (float*)smem;
    #pragma unroll
    for (int R = 0; R < 2; ++R) {
        #pragma unroll
        for (int q2 = 0; q2 < 2; ++q2) {
            const int qb = R * 2 + q2;
            #pragma unroll
            for (int nt = 0; nt < 4; ++nt) {
                const int cd = nt * 2 + (l16 >> 3);      // data d-chunk
                #pragma unroll
                for (int r = 0; r < 4; ++r) {
                    const int q  = quad * 4 + r;
                    const int cs = cd ^ (q & 7);         // swizzled slot
                    part[((wv * 2 + q2) * 16 + q) * 64 + cs * 8 + (l16 & 7)] =
                        o[qb][nt][r];
                }
            }
        }
        __syncthreads();

        const float lf = R ? lB : lA;
        const int cs = chnk ^ (qrow & 7);
        float r0[8] = {0, 0, 0, 0, 0, 0, 0, 0};
        #pragma unroll
        for (int w = 0; w < 4; ++w) {
            const float* pp = &part[((w * 2 + qb2) * 16 + qrow) * 64 + cs * 8];
            const float4 a = *(const float4*)pp;
            const float4 c = *(const float4*)(pp + 4);
            r0[0] += a.x; r0[1] += a.y; r0[2] += a.z; r0[3] += a.w;
            r0[4] += c.x; r0[5] += c.y; r0[6] += c.z; r0[7] += c.w;
        }
        const int qg = qt * 64 + (R * 2 + qb2) * 16 + qrow;
        float* op = O + ((size_t)b * TSEQ + qg) * DMODEL + h * DHEAD + chnk * 8;
        const float inv = 1.f / lf;
        float4 w0 = {r0[0] * inv, r0[1] * inv, r0[2] * inv, r0[3] * inv};
        float4 w1 = {r0[4] * inv, r0[5] * inv, r0[6] * inv, r0[7] * inv};
        *(float4*)op = w0;
        *(float4*)(op + 4) = w1;
        __syncthreads();                    // round A reads done before round B
    }
}

extern "C" void kernel_launch(void* const* d_in, const int* in_sizes, int n_in,
                              void* d_out, int out_size, void* d_ws, size_t ws_size,
                              hipStream_t stream) {
    const float* q = (const float*)d_in[0];
    const float* k = (const float*)d_in[1];
    const float* v = (const float*)d_in[2];
    float* out = (float*)d_out;

    _Float16* Kh = (_Float16*)d_ws;                                  // 8.4 MB
    _Float16* Vh = Kh + (size_t)BATCH * N_HEAD * TSEQ * DHEAD;       // 8.4 MB

    prep<<<dim3(TSEQ / 64, BATCH * N_HEAD), 256, 0, stream>>>(k, v, Kh, Vh);
    alibi_attn<<<dim3(BATCH * N_HEAD, 32), 256, 0, stream>>>(q, Kh, Vh, out);
}